// Round 1
// baseline (1381.923 us; speedup 1.0000x reference)
//
#include <hip/hip_runtime.h>
#include <hip/hip_bf16.h>

#define HH 64      // hidden
#define TT 256     // seq len
#define NB 1024    // batch
#define GG 256     // 4*H gates
#define DD0 5      // layer-0 input dim
#define DD1 128    // layer-1 input dim (2*H)

__device__ __forceinline__ float sigf(float x) { return 1.0f / (1.0f + __expf(-x)); }
__device__ __forceinline__ float tanh_fast(float x) { return 2.0f / (1.0f + __expf(-2.0f * x)) - 1.0f; }

// ---------------------------------------------------------------------------
// Layer 0: both directions. grid = 512 blocks (dir = bid>>8), 256 threads,
// 4 batch rows per block. Thread j owns gate j for all 4 rows.
// Writes out0[b][t][dir*64 + u].
// ---------------------------------------------------------------------------
template <bool BF16OUT>
__launch_bounds__(256, 2)
__global__ void lstm_l0(const float* __restrict__ x,
                        const float* __restrict__ w_ih_f, const float* __restrict__ w_hh_f,
                        const float* __restrict__ b_ih_f, const float* __restrict__ b_hh_f,
                        const float* __restrict__ w_ih_r, const float* __restrict__ w_hh_r,
                        const float* __restrict__ b_ih_r, const float* __restrict__ b_hh_r,
                        void* __restrict__ out0) {
    const int tid  = threadIdx.x;
    const int dir  = blockIdx.x >> 8;
    const int row0 = (blockIdx.x & 255) * 4;

    const float* w_ih = dir ? w_ih_r : w_ih_f;
    const float* w_hh = dir ? w_hh_r : w_hh_f;
    const float* b_ih = dir ? b_ih_r : b_ih_f;
    const float* b_hh = dir ? b_hh_r : b_hh_f;

    __shared__ __align__(16) float xs[4 * TT * DD0];  // 20 KB: x for 4 rows, all t
    __shared__ __align__(16) float hs[4 * HH];        // 1 KB
    __shared__ __align__(16) float gs[4 * GG];        // 4 KB

    // stage x: 4 rows x 1280 contiguous floats
    for (int i = tid; i < 4 * TT * DD0; i += 256)
        xs[i] = x[(size_t)row0 * TT * DD0 + i];
    hs[tid] = 0.0f;  // 256 == 4*64

    // per-thread weights in registers
    float whh[HH];
#pragma unroll
    for (int k = 0; k < HH; ++k) whh[k] = w_hh[tid * HH + k];
    float wih[DD0];
#pragma unroll
    for (int d = 0; d < DD0; ++d) wih[d] = w_ih[tid * DD0 + d];
    const float bias = b_ih[tid] + b_hh[tid];

    const int r = tid >> 6, u = tid & 63;  // update-phase ownership
    float c = 0.0f;

    __syncthreads();

    for (int t = 0; t < TT; ++t) {
        const int tt = dir ? (TT - 1 - t) : t;
        // ---- gate phase: gate j for rows 0..3 ----
#pragma unroll
        for (int rr = 0; rr < 4; ++rr) {
            float a0 = bias, a1 = 0.f, a2 = 0.f, a3 = 0.f;
#pragma unroll
            for (int d = 0; d < DD0; ++d) a0 += wih[d] * xs[rr * TT * DD0 + tt * DD0 + d];
            const float4* h4 = (const float4*)&hs[rr * HH];
#pragma unroll
            for (int kk = 0; kk < 16; ++kk) {
                float4 hv = h4[kk];  // broadcast read (all lanes same addr)
                a0 += whh[4 * kk + 0] * hv.x;
                a1 += whh[4 * kk + 1] * hv.y;
                a2 += whh[4 * kk + 2] * hv.z;
                a3 += whh[4 * kk + 3] * hv.w;
            }
            gs[rr * GG + tid] = (a0 + a1) + (a2 + a3);
        }
        __syncthreads();
        // ---- update phase: this thread owns (r, u) ----
        {
            float gi = gs[r * GG + u], gf = gs[r * GG + u + 64];
            float gc = gs[r * GG + u + 128], go = gs[r * GG + u + 192];
            c = sigf(gf) * c + sigf(gi) * tanh_fast(gc);
            float h = sigf(go) * tanh_fast(c);
            hs[r * HH + u] = h;
            size_t oidx = (size_t)(row0 + r) * TT * DD1 + (size_t)tt * DD1 + dir * HH + u;
            if (BF16OUT) ((__hip_bfloat16*)out0)[oidx] = __float2bfloat16(h);
            else         ((float*)out0)[oidx] = h;
        }
        __syncthreads();
    }
}

// ---------------------------------------------------------------------------
// Layer 1 forward only. grid = 256 blocks, 256 threads, 4 rows/block.
// Input projection (128->256) fused into the recurrence; input tile double-
// buffered in LDS with one-step prefetch. Only final h is stored.
// ---------------------------------------------------------------------------
template <bool BF16IN>
__launch_bounds__(256, 1)
__global__ void lstm_l1(const void* __restrict__ in0,
                        const float* __restrict__ w_ih, const float* __restrict__ w_hh,
                        const float* __restrict__ b_ih, const float* __restrict__ b_hh,
                        float* __restrict__ h_last) {
    const int tid  = threadIdx.x;
    const int row0 = blockIdx.x * 4;

    __shared__ __align__(16) float ins[2][4 * DD1];  // 4 KB double buffer
    __shared__ __align__(16) float hs[4 * HH];
    __shared__ __align__(16) float gs[4 * GG];

    float wihr[DD1];
#pragma unroll
    for (int k = 0; k < DD1; ++k) wihr[k] = w_ih[tid * DD1 + k];
    float whh[HH];
#pragma unroll
    for (int k = 0; k < HH; ++k) whh[k] = w_hh[tid * HH + k];
    const float bias = b_ih[tid] + b_hh[tid];

    const int r = tid >> 6, u = tid & 63;
    const int pr = tid >> 6;              // prefetch row (same partition)
    const int pk = (tid * 2) & 127;       // prefetch col
    float c = 0.0f;

    auto load_in = [&](int t, float2* v) {
        size_t base = ((size_t)(row0 + pr) * TT + t) * DD1 + pk;
        if (BF16IN) {
            const __hip_bfloat16* p = (const __hip_bfloat16*)in0 + base;
            v->x = __bfloat162float(p[0]);
            v->y = __bfloat162float(p[1]);
        } else {
            *v = *(const float2*)((const float*)in0 + base);
        }
    };

    hs[tid] = 0.0f;
    {   // stage t = 0
        float2 v;
        load_in(0, &v);
        ((float2*)ins[0])[tid] = v;
    }
    __syncthreads();

    for (int t = 0; t < TT; ++t) {
        const int cur = t & 1;
        float2 pf;
        if (t + 1 < TT) load_in(t + 1, &pf);  // issue early; hidden under gates
        // ---- gate phase ----
#pragma unroll
        for (int rr = 0; rr < 4; ++rr) {
            float a0 = bias, a1 = 0.f, a2 = 0.f, a3 = 0.f;
            const float4* in4 = (const float4*)&ins[cur][rr * DD1];
#pragma unroll
            for (int kk = 0; kk < 32; ++kk) {
                float4 iv = in4[kk];
                a0 += wihr[4 * kk + 0] * iv.x;
                a1 += wihr[4 * kk + 1] * iv.y;
                a2 += wihr[4 * kk + 2] * iv.z;
                a3 += wihr[4 * kk + 3] * iv.w;
            }
            const float4* h4 = (const float4*)&hs[rr * HH];
#pragma unroll
            for (int kk = 0; kk < 16; ++kk) {
                float4 hv = h4[kk];
                a0 += whh[4 * kk + 0] * hv.x;
                a1 += whh[4 * kk + 1] * hv.y;
                a2 += whh[4 * kk + 2] * hv.z;
                a3 += whh[4 * kk + 3] * hv.w;
            }
            gs[rr * GG + tid] = (a0 + a1) + (a2 + a3);
        }
        __syncthreads();
        // ---- update ----
        float gi = gs[r * GG + u], gf = gs[r * GG + u + 64];
        float gc = gs[r * GG + u + 128], go = gs[r * GG + u + 192];
        c = sigf(gf) * c + sigf(gi) * tanh_fast(gc);
        float h = sigf(go) * tanh_fast(c);
        hs[r * HH + u] = h;
        if (t + 1 < TT) ((float2*)ins[cur ^ 1])[tid] = pf;
        if (t == TT - 1) h_last[(size_t)(row0 + r) * HH + u] = h;
        __syncthreads();
    }
}

// ---------------------------------------------------------------------------
// Tail: layer-1 backward is ONE step at t = T-1 from zero state (h0=0 kills
// the w_hh term), then FC. grid = 1024 blocks (one per batch), 256 threads.
// ---------------------------------------------------------------------------
template <bool BF16IN>
__global__ void lstm_tail(const void* __restrict__ in0,
                          const float* __restrict__ h1f,
                          const float* __restrict__ w_ih_r,
                          const float* __restrict__ b_ih_r, const float* __restrict__ b_hh_r,
                          const float* __restrict__ fc_w, const float* __restrict__ fc_b,
                          float* __restrict__ out) {
    const int b   = blockIdx.x;
    const int tid = threadIdx.x;
    __shared__ __align__(16) float insl[DD1];
    __shared__ __align__(16) float hb[HH];
    __shared__ __align__(16) float gsh[GG];

    if (tid < DD1) {
        size_t base = ((size_t)b * TT + (TT - 1)) * DD1 + tid;
        insl[tid] = BF16IN ? __bfloat162float(((const __hip_bfloat16*)in0)[base])
                           : ((const float*)in0)[base];
    }
    __syncthreads();

    float a0 = b_ih_r[tid] + b_hh_r[tid], a1 = 0.f, a2 = 0.f, a3 = 0.f;
    const float4* in4 = (const float4*)insl;
#pragma unroll
    for (int kk = 0; kk < 32; ++kk) {
        float4 iv = in4[kk];
        float4 wv = *(const float4*)&w_ih_r[tid * DD1 + 4 * kk];
        a0 += wv.x * iv.x;
        a1 += wv.y * iv.y;
        a2 += wv.z * iv.z;
        a3 += wv.w * iv.w;
    }
    gsh[tid] = (a0 + a1) + (a2 + a3);
    __syncthreads();

    if (tid < HH) {
        float gi = gsh[tid], gc = gsh[tid + 128], go = gsh[tid + 192];
        float cc = sigf(gi) * tanh_fast(gc);  // c_prev = 0
        hb[tid] = sigf(go) * tanh_fast(cc);
    }
    __syncthreads();

    if (tid < 64) {
        float p = fc_w[tid] * h1f[(size_t)b * HH + tid] + fc_w[HH + tid] * hb[tid];
#pragma unroll
        for (int off = 32; off; off >>= 1) p += __shfl_xor(p, off);
        if (tid == 0) out[b] = p + fc_b[0];
    }
}

// ---------------------------------------------------------------------------
extern "C" void kernel_launch(void* const* d_in, const int* in_sizes, int n_in,
                              void* d_out, int out_size, void* d_ws, size_t ws_size,
                              hipStream_t stream) {
    const float* x = (const float*)d_in[0];
    // l0 fwd: 1..4, l0 rev: 5..8, l1 fwd: 9..12, l1 rev: 13..16, fc: 17,18
    const size_t out0_f32_bytes = (size_t)NB * TT * DD1 * sizeof(float);  // 134 MB
    const size_t hlast_bytes    = (size_t)NB * HH * sizeof(float);

    const bool bf16 = (ws_size < out0_f32_bytes + hlast_bytes);
    char* ws = (char*)d_ws;
    void* out0 = (void*)ws;
    const size_t out0_bytes = bf16 ? out0_f32_bytes / 2 : out0_f32_bytes;
    float* h1f = (float*)(ws + out0_bytes);

    if (!bf16) {
        lstm_l0<false><<<512, 256, 0, stream>>>(
            x, (const float*)d_in[1], (const float*)d_in[2], (const float*)d_in[3], (const float*)d_in[4],
            (const float*)d_in[5], (const float*)d_in[6], (const float*)d_in[7], (const float*)d_in[8], out0);
        lstm_l1<false><<<256, 256, 0, stream>>>(
            out0, (const float*)d_in[9], (const float*)d_in[10], (const float*)d_in[11], (const float*)d_in[12], h1f);
        lstm_tail<false><<<1024, 256, 0, stream>>>(
            out0, h1f, (const float*)d_in[13], (const float*)d_in[15], (const float*)d_in[16],
            (const float*)d_in[17], (const float*)d_in[18], (float*)d_out);
    } else {
        lstm_l0<true><<<512, 256, 0, stream>>>(
            x, (const float*)d_in[1], (const float*)d_in[2], (const float*)d_in[3], (const float*)d_in[4],
            (const float*)d_in[5], (const float*)d_in[6], (const float*)d_in[7], (const float*)d_in[8], out0);
        lstm_l1<true><<<256, 256, 0, stream>>>(
            out0, (const float*)d_in[9], (const float*)d_in[10], (const float*)d_in[11], (const float*)d_in[12], h1f);
        lstm_tail<true><<<1024, 256, 0, stream>>>(
            out0, h1f, (const float*)d_in[13], (const float*)d_in[15], (const float*)d_in[16],
            (const float*)d_in[17], (const float*)d_in[18], (float*)d_out);
    }
}